// Round 5
// baseline (682.211 us; speedup 1.0000x reference)
//
#include <hip/hip_runtime.h>

// Problem dims (fixed by reference setup_inputs)
#define TT 512
#define BB 8
#define HH 512
#define VV 32000
#define RR (TT * BB)   // 4096 rows (t,b)

__device__ __forceinline__ float clip01(float x) { return fminf(fmaxf(x, 0.0f), 1.0f); }

// ---------------------------------------------------------------------------
// Mega-kernel: all three LIF layers fused. 8 blocks (one per batch lane b),
// 512 threads (one per hidden unit h). The inter-layer coupling (H x H matmul
// on 0/1 spikes) only needs the PREVIOUS layer's spike list for the same b —
// which this block itself produced. Phases separated by __syncthreads();
// spike counts in LDS; spike index lists in global (read back only on the
// rare nonzero path).
// ---------------------------------------------------------------------------
__global__ void __launch_bounds__(512) snn_scan_kernel(
        const int* __restrict__ x, const float* __restrict__ emb,
        const float* __restrict__ pos,
        const float* __restrict__ beta1, const float* __restrict__ beta2,
        const float* __restrict__ beta3,
        const float* __restrict__ W2, const float* __restrict__ b2,
        const float* __restrict__ W3, const float* __restrict__ b3,
        int* __restrict__ act1, int* __restrict__ act2, int* __restrict__ act3,
        int* __restrict__ cnt3_g) {
    __shared__ int x_lds[TT];
    __shared__ int c1[TT], c2[TT], c3[TT];
    const int b = blockIdx.x;    // 0..7
    const int h = threadIdx.x;   // 0..511 (doubles as t-index for preloads)

    x_lds[h] = x[h * BB + b];    // x is [T,B]; t == threadIdx here
    c1[h] = 0; c2[h] = 0; c3[h] = 0;
    __syncthreads();

    // ---- phase 1: embedding-driven LIF ----
    {
        float bt = clip01(beta1[h]);
        float m = 0.0f;
        for (int t0 = 0; t0 < TT; t0 += 32) {
            float ev[32], pv[32];
#pragma unroll
            for (int u = 0; u < 32; ++u) {
                int xv = x_lds[t0 + u];
                ev[u] = emb[((size_t)xv << 9) + h];
                pv[u] = pos[((t0 + u) << 9) + h];
            }
#pragma unroll
            for (int u = 0; u < 32; ++u) {
                float inp = ev[u] + pv[u];
                // reset = spike(m_prev-1); m = beta*m_prev + inp - reset; spk = spike(m-1)
                float reset = (m > 1.0f) ? 1.0f : 0.0f;  // (m-1>0) == (m>1) exactly in fp32
                m = bt * m + inp - reset;
                if (m > 1.0f) {
                    int t = t0 + u;
                    int p = atomicAdd(&c1[t], 1);
                    act1[((t * BB + b) << 9) + p] = h;
                }
            }
        }
    }
    __syncthreads();   // publish c1 (LDS) + act1 (global, same-CU L1) to the block

    // ---- phase 2: hidden layer 2 (fused sparse matmul + LIF) ----
    {
        float bh = b2[h];
        float inp0 = fmaxf(bh, 0.0f);
        float bt = clip01(beta2[h]);
        float m = 0.0f;
        for (int t0 = 0; t0 < TT; t0 += 16) {
            int n[16];
#pragma unroll
            for (int u = 0; u < 16; ++u) n[u] = c1[t0 + u];
#pragma unroll
            for (int u = 0; u < 16; ++u) {
                float inp;
                if (n[u] == 0) {
                    inp = inp0;
                } else {
                    float acc = bh;
                    const int* a = act1 + (((t0 + u) * BB + b) << 9);
                    for (int i = 0; i < n[u]; ++i) acc += W2[(h << 9) + a[i]];
                    inp = fmaxf(acc, 0.0f);
                }
                float reset = (m > 1.0f) ? 1.0f : 0.0f;
                m = bt * m + inp - reset;
                if (m > 1.0f) {
                    int t = t0 + u;
                    int p = atomicAdd(&c2[t], 1);
                    act2[((t * BB + b) << 9) + p] = h;
                }
            }
        }
    }
    __syncthreads();

    // ---- phase 3: hidden layer 3 ----
    {
        float bh = b3[h];
        float inp0 = fmaxf(bh, 0.0f);
        float bt = clip01(beta3[h]);
        float m = 0.0f;
        for (int t0 = 0; t0 < TT; t0 += 16) {
            int n[16];
#pragma unroll
            for (int u = 0; u < 16; ++u) n[u] = c2[t0 + u];
#pragma unroll
            for (int u = 0; u < 16; ++u) {
                float inp;
                if (n[u] == 0) {
                    inp = inp0;
                } else {
                    float acc = bh;
                    const int* a = act2 + (((t0 + u) * BB + b) << 9);
                    for (int i = 0; i < n[u]; ++i) acc += W3[(h << 9) + a[i]];
                    inp = fmaxf(acc, 0.0f);
                }
                float reset = (m > 1.0f) ? 1.0f : 0.0f;
                m = bt * m + inp - reset;
                if (m > 1.0f) {
                    int t = t0 + u;
                    int p = atomicAdd(&c3[t], 1);
                    act3[((t * BB + b) << 9) + p] = h;
                }
            }
        }
    }
    __syncthreads();
    cnt3_g[h * BB + b] = c3[h];   // h doubles as t; export layer-3 counts
}

// ---------------------------------------------------------------------------
// Output GEMM: out[r][v] = bout[v] + sum_{k in act3[r]} Wout[v][k].
// Spikes are exactly 0/1, so summing selected columns is exact. Write-BW
// bound (524 MB): PLAIN float4 stores this round (A/B test vs R4's
// nontemporal — suspect nt degraded the write path below the 6.3 TB/s the
// rocclr fills demonstrate).
// ---------------------------------------------------------------------------
__global__ void __launch_bounds__(512) out_gemm_kernel(
        const int* __restrict__ cnt, const int* __restrict__ act,
        const float* __restrict__ Wout, const float* __restrict__ bout,
        float* __restrict__ out) {
    int v = blockIdx.x * 2048 + threadIdx.x * 4;
    if (v >= VV) return;
    float4 bv = *(const float4*)(bout + v);
    int r0 = blockIdx.y * 8;
#pragma unroll
    for (int rr = 0; rr < 8; ++rr) {
        int r = r0 + rr;
        int n = cnt[r];
        float4 acc = bv;
        const int* a = act + (r << 9);
        for (int i = 0; i < n; ++i) {
            int k = a[i];
            acc.x += Wout[(size_t)(v + 0) * HH + k];
            acc.y += Wout[(size_t)(v + 1) * HH + k];
            acc.z += Wout[(size_t)(v + 2) * HH + k];
            acc.w += Wout[(size_t)(v + 3) * HH + k];
        }
        *(float4*)(out + (size_t)r * VV + v) = acc;   // plain store (A/B vs nontemporal)
    }
}

extern "C" void kernel_launch(void* const* d_in, const int* in_sizes, int n_in,
                              void* d_out, int out_size, void* d_ws, size_t ws_size,
                              hipStream_t stream) {
    const int*   x     = (const int*)d_in[0];
    const float* emb   = (const float*)d_in[1];
    const float* pos   = (const float*)d_in[2];
    const float* beta1 = (const float*)d_in[3];
    const float* beta2 = (const float*)d_in[4];
    const float* beta3 = (const float*)d_in[5];
    const float* W2    = (const float*)d_in[6];
    const float* b2    = (const float*)d_in[7];
    const float* W3    = (const float*)d_in[8];
    const float* b3    = (const float*)d_in[9];
    const float* Wout  = (const float*)d_in[10];
    const float* bout  = (const float*)d_in[11];
    float* out = (float*)d_out;

    // ws layout: act1 | act2 | act3 (R*H i32 each) | cnt3 (R i32)
    int* act1 = (int*)d_ws;
    int* act2 = act1 + (size_t)RR * HH;
    int* act3 = act2 + (size_t)RR * HH;
    int* cnt3 = act3 + (size_t)RR * HH;

    snn_scan_kernel<<<BB, HH, 0, stream>>>(x, emb, pos, beta1, beta2, beta3,
                                           W2, b2, W3, b3, act1, act2, act3, cnt3);
    out_gemm_kernel<<<dim3(16, RR / 8), HH, 0, stream>>>(cnt3, act3, Wout, bout, out);
}